// Round 12
// baseline (427.640 us; speedup 1.0000x reference)
//
#include <hip/hip_runtime.h>
#include <math.h>

#define NN 10000
#define HEADS 8
#define NCLS 40
#define CHK 64
#define LOG2E 1.4426950408889634f

typedef __attribute__((ext_vector_type(8))) short short8;
typedef __attribute__((ext_vector_type(8))) unsigned short ushort8v;
typedef __attribute__((ext_vector_type(4))) float floatx4;

static __device__ __forceinline__ short f2bf(float f) {
    unsigned u = __builtin_bit_cast(unsigned, f);
    unsigned r = (u + 0x7fff + ((u >> 16) & 1)) >> 16;
    return (short)r;
}
static __device__ __forceinline__ float bf2f(unsigned short u) {
    unsigned x = ((unsigned)u) << 16;
    return __builtin_bit_cast(float, x);
}
static __device__ __forceinline__ void gl2lds16(const void* g, void* l) {
    __builtin_amdgcn_global_load_lds(
        (const __attribute__((address_space(1))) unsigned int*)g,
        (__attribute__((address_space(3))) unsigned int*)l, 16, 0, 0);
}

// ---------------- layer-0 GEMM: BM=64, BN=128, BK=64, SINGLE-buffer (24 KB) ----------
// Single-buffer kept on purpose: this launch carries latency-bound tail blocks
// (scatter atomics, W1 prep) that want max blocks/CU (r6 post-mortem).
// A staged from f32 with fused bf16 cast. Fused epilogue: per-head scores.
__global__ __launch_bounds__(256) void gemm_bf16_w128(
    const float* __restrict__ Af32, const short* __restrict__ Bt,
    short* __restrict__ Cbf,
    const float* __restrict__ asrc, const float* __restrict__ adst,
    float* __restrict__ s0,
    const int* __restrict__ esrc, const int* __restrict__ edst,
    int* __restrict__ cursor, int* __restrict__ elist, int E, int scatBlocks,
    const float* __restrict__ W1, const float* __restrict__ a_src1,
    const float* __restrict__ a_dst1, float* __restrict__ v1,
    short* __restrict__ W1pT,
    int gemmBlocks, int gridY,
    int M, int Nn, int K, float alpha)
{
    __shared__ short As[64 * 64];    // 8 KB (aliased as f32 transpose tile in tails)
    __shared__ short Bs[128 * 64];   // 16 KB
    const int tid = threadIdx.x;
    if ((int)blockIdx.x >= gemmBlocks) {
        int td = (int)blockIdx.x - gemmBlocks;
        if (td < scatBlocks) {               // CSR edge scatter
            int e = td * 256 + tid;
            if (e < E) {
                int dn = edst[e];
                int pos = atomicAdd(&cursor[dn], 1);
                elist[pos] = esrc[e];
            }
            return;
        }
        td -= scatBlocks;
        if (td < 16) {                       // v1 = folded W1·a  [256 f][16 j]
            int idx = td * 256 + tid;
            int f = idx >> 4, j = idx & 15;
            int h = j & 7;
            const float* a = (j < 8) ? a_src1 : a_dst1;
            float s = 0.f;
            for (int c = 0; c < 256; c++)
                s += W1[f * 2048 + h * 256 + c] * a[h * 256 + c];
            v1[idx] = s;
            return;
        }
        td -= 16;
        {                                    // W1pT bf16 [256 c][2048 hf], td in [0,512)
            float (*tile)[33] = (float(*)[33])As;
            int h = td >> 6, f0 = ((td >> 3) & 7) * 32, c0 = (td & 7) * 32;
            int tx = tid & 31, ty = tid >> 5;
            for (int r = ty; r < 32; r += 8)
                tile[r][tx] = W1[(size_t)(f0 + r) * 2048 + h * 256 + c0 + tx];
            __syncthreads();
            for (int r = ty; r < 32; r += 8)
                W1pT[(size_t)(c0 + r) * 2048 + h * 256 + f0 + tx] = f2bf(tile[tx][r]);
            return;
        }
    }
    const int w = tid >> 6, L = tid & 63;
    const int quad = L >> 4, lr = L & 15;
    const int d = blockIdx.x;
    const int by = (d >> 4) * 8 + (d & 7);   // pair (bx=0,by),(bx=1,by) differ by 8 -> same XCD
    const int bx = (d >> 3) & 1;
    if (by >= gridY) return;
    const int col0 = bx * 128, row0 = by * 64;

    const int schunk = (L & 7) ^ (L >> 3);   // (row&7)==(L>>3) for all staged rows
    const int sarow = w * 16 + (L >> 3);
    int ga0 = row0 + sarow;     if (ga0 > M - 1) ga0 = M - 1;
    int ga1 = row0 + sarow + 8; if (ga1 > M - 1) ga1 = M - 1;
    const float* axp0 = Af32 + (size_t)ga0 * K + schunk * 8;
    const float* axp1 = Af32 + (size_t)ga1 * K + schunk * 8;
    short* alw0 = &As[w * 1024 + L * 8];     // == gl2lds16 dest: base + L*16 bytes
    short* alw1 = &As[w * 1024 + 512 + L * 8];
    const int sbrow = w * 32 + (L >> 3);
    int gb[4];
    #pragma unroll
    for (int c = 0; c < 4; c++) {
        gb[c] = col0 + sbrow + c * 8;
        if (gb[c] > Nn - 1) gb[c] = Nn - 1;
    }
    const short* bgp0 = Bt + (size_t)gb[0] * K + schunk * 8;
    const short* bgp1 = Bt + (size_t)gb[1] * K + schunk * 8;
    const short* bgp2 = Bt + (size_t)gb[2] * K + schunk * 8;
    const short* bgp3 = Bt + (size_t)gb[3] * K + schunk * 8;
    short* blp0 = &Bs[w * 2048];
    short* blp1 = &Bs[w * 2048 + 512];
    short* blp2 = &Bs[w * 2048 + 1024];
    short* blp3 = &Bs[w * 2048 + 1536];

    floatx4 acc[4][2];
    const floatx4 zf = {0.f, 0.f, 0.f, 0.f};
    #pragma unroll
    for (int i = 0; i < 4; i++)
        #pragma unroll
        for (int j = 0; j < 2; j++) acc[i][j] = zf;

    for (int k0 = 0; k0 < K; k0 += 64) {
        gl2lds16(bgp0 + k0, blp0);           // B DMA first: flies under A cast
        gl2lds16(bgp1 + k0, blp1);
        gl2lds16(bgp2 + k0, blp2);
        gl2lds16(bgp3 + k0, blp3);
        {                                    // f32 A, fused bf16 cast
            floatx4 va0 = *(const floatx4*)(axp0 + k0);
            floatx4 va1 = *(const floatx4*)(axp0 + k0 + 4);
            floatx4 vb0 = *(const floatx4*)(axp1 + k0);
            floatx4 vb1 = *(const floatx4*)(axp1 + k0 + 4);
            short8 o0, o1;
            #pragma unroll
            for (int q = 0; q < 8; q++) {
                o0[q] = f2bf(q < 4 ? va0[q & 3] : va1[q & 3]);
                o1[q] = f2bf(q < 4 ? vb0[q & 3] : vb1[q & 3]);
            }
            *(short8*)alw0 = o0;
            *(short8*)alw1 = o1;
        }
        __syncthreads();
        #pragma unroll
        for (int ks = 0; ks < 2; ks++) {
            const int sl = ((ks * 4 + quad) ^ (lr & 7)) * 8;
            short8 bfr[2];
            #pragma unroll
            for (int j = 0; j < 2; j++)
                bfr[j] = *(const short8*)&Bs[(w * 32 + j * 16 + lr) * 64 + sl];
            #pragma unroll
            for (int i = 0; i < 4; i++) {
                short8 afr = *(const short8*)&As[(i * 16 + lr) * 64 + sl];
                #pragma unroll
                for (int j = 0; j < 2; j++)
                    acc[i][j] = __builtin_amdgcn_mfma_f32_16x16x32_bf16(afr, bfr[j], acc[i][j], 0, 0, 0);
            }
        }
        __syncthreads();
    }
    #pragma unroll
    for (int j = 0; j < 2; j++) {
        int ccol = col0 + w * 32 + j * 16 + lr;
        if (ccol >= Nn) continue;
        #pragma unroll
        for (int i = 0; i < 4; i++) {
            #pragma unroll
            for (int r = 0; r < 4; r++) {
                int crow = row0 + i * 16 + quad * 4 + r;
                if (crow < M)
                    Cbf[(size_t)crow * Nn + ccol] = f2bf(alpha * acc[i][j][r]);
            }
        }
    }
    {          // fused layer-0 per-head scores from f32 acc (head fully inside wave)
        const int head = bx * 4 + w;
        float as0 = asrc[col0 + w * 32 + lr];
        float as1 = asrc[col0 + w * 32 + 16 + lr];
        float ad0 = adst[col0 + w * 32 + lr];
        float ad1 = adst[col0 + w * 32 + 16 + lr];
        #pragma unroll
        for (int i = 0; i < 4; i++) {
            #pragma unroll
            for (int r = 0; r < 4; r++) {
                float ps = acc[i][0][r] * as0 + acc[i][1][r] * as1;
                float pd = acc[i][0][r] * ad0 + acc[i][1][r] * ad1;
                #pragma unroll
                for (int off = 1; off < 16; off <<= 1) {
                    ps += __shfl_xor(ps, off, 64);
                    pd += __shfl_xor(pd, off, 64);
                }
                if (lr == 0) {
                    int crow = row0 + i * 16 + quad * 4 + r;
                    if (crow < M) {
                        s0[crow * 16 + head] = alpha * ps;
                        s0[crow * 16 + 8 + head] = alpha * pd;
                    }
                }
            }
        }
    }
}

// ---------------- layer-1 GEMM: BM=32, BN=128, BK=64, 2-phase double-buffer ----------
// 626 live blocks (2.45/CU co-resident at 40 KB LDS): inter-block TLP hides the
// per-iteration barrier stall the prefetch alone can't (r9/r10 post-mortem).
__global__ __launch_bounds__(256) void gemm1_db(
    const short* __restrict__ A, const short* __restrict__ Bt,
    float* __restrict__ C, float* __restrict__ stats,
    int gridY, int M, int Nn, int K, float alpha)
{
    __shared__ short As[2][32 * 64];     // 8 KB
    __shared__ short Bs[2][128 * 64];    // 32 KB
    const int tid = threadIdx.x;
    const int w = tid >> 6, L = tid & 63;
    const int quad = L >> 4, lr = L & 15;
    const int d = blockIdx.x;
    const int by = (d >> 4) * 8 + (d & 7);   // pair (bx=0,by),(bx=1,by) differ by 8 -> same XCD
    const int bx = (d >> 3) & 1;
    if (by >= gridY) return;
    const int col0 = bx * 128, row0 = by * 32;

    const int schunk = (L & 7) ^ (L >> 3);
    int ga = row0 + w * 8 + (L >> 3); if (ga > M - 1) ga = M - 1;
    const short* agp = A + (size_t)ga * K + schunk * 8;
    const int sbrow = w * 32 + (L >> 3);
    int gb[4];
    #pragma unroll
    for (int c = 0; c < 4; c++) {
        gb[c] = col0 + sbrow + c * 8;
        if (gb[c] > Nn - 1) gb[c] = Nn - 1;
    }
    const short* bgp0 = Bt + (size_t)gb[0] * K + schunk * 8;
    const short* bgp1 = Bt + (size_t)gb[1] * K + schunk * 8;
    const short* bgp2 = Bt + (size_t)gb[2] * K + schunk * 8;
    const short* bgp3 = Bt + (size_t)gb[3] * K + schunk * 8;

    floatx4 acc[2][2];
    const floatx4 zf = {0.f, 0.f, 0.f, 0.f};
    #pragma unroll
    for (int i = 0; i < 2; i++)
        #pragma unroll
        for (int j = 0; j < 2; j++) acc[i][j] = zf;

    const int nt = K >> 6;
    gl2lds16(agp,  &As[0][w * 512]);
    gl2lds16(bgp0, &Bs[0][w * 2048]);
    gl2lds16(bgp1, &Bs[0][w * 2048 + 512]);
    gl2lds16(bgp2, &Bs[0][w * 2048 + 1024]);
    gl2lds16(bgp3, &Bs[0][w * 2048 + 1536]);
    __syncthreads();
    int cur = 0;
    for (int t = 0; t < nt; t++) {
        if (t + 1 < nt) {                    // prefetch next tile into other buffer
            const int k0 = (t + 1) << 6;
            const int nb = cur ^ 1;
            gl2lds16(agp + k0,  &As[nb][w * 512]);
            gl2lds16(bgp0 + k0, &Bs[nb][w * 2048]);
            gl2lds16(bgp1 + k0, &Bs[nb][w * 2048 + 512]);
            gl2lds16(bgp2 + k0, &Bs[nb][w * 2048 + 1024]);
            gl2lds16(bgp3 + k0, &Bs[nb][w * 2048 + 1536]);
        }
        #pragma unroll
        for (int ks = 0; ks < 2; ks++) {
            const int sl = ((ks * 4 + quad) ^ (lr & 7)) * 8;
            short8 bfr[2];
            #pragma unroll
            for (int j = 0; j < 2; j++)
                bfr[j] = *(const short8*)&Bs[cur][(w * 32 + j * 16 + lr) * 64 + sl];
            #pragma unroll
            for (int i = 0; i < 2; i++) {
                short8 afr = *(const short8*)&As[cur][(i * 16 + lr) * 64 + sl];
                #pragma unroll
                for (int j = 0; j < 2; j++)
                    acc[i][j] = __builtin_amdgcn_mfma_f32_16x16x32_bf16(afr, bfr[j], acc[i][j], 0, 0, 0);
            }
        }
        __syncthreads();                     // prefetch landed + ds_reads done
        cur ^= 1;
    }
    float s[2] = {0.f, 0.f}, s2[2] = {0.f, 0.f};
    #pragma unroll
    for (int j = 0; j < 2; j++) {
        int ccol = col0 + w * 32 + j * 16 + lr;
        if (ccol >= Nn) continue;
        #pragma unroll
        for (int i = 0; i < 2; i++) {
            #pragma unroll
            for (int r = 0; r < 4; r++) {
                int crow = row0 + i * 16 + quad * 4 + r;
                if (crow < M) {
                    float v = alpha * acc[i][j][r];
                    C[(size_t)crow * Nn + ccol] = v;
                    s[j] += v; s2[j] += v * v;
                }
            }
        }
    }
    #pragma unroll
    for (int j = 0; j < 2; j++) {
        s[j]  += __shfl_xor(s[j], 16, 64);  s[j]  += __shfl_xor(s[j], 32, 64);
        s2[j] += __shfl_xor(s2[j], 16, 64); s2[j] += __shfl_xor(s2[j], 32, 64);
    }
    if (L < 16) {
        #pragma unroll
        for (int j = 0; j < 2; j++) {
            int ccol = col0 + w * 32 + j * 16 + L;
            if (ccol < Nn) {
                atomicAdd(&stats[ccol], s[j]);
                atomicAdd(&stats[256 + ccol], s2[j]);
            }
        }
    }
}

// ---------------- classifier GEMM, BM=32, 2-phase pipelined, fused BN+ELU+residual -----
__global__ __launch_bounds__(256) void classifier_fused(
    const float* __restrict__ X, const float* __restrict__ stats,
    const float* __restrict__ g, const float* __restrict__ be,
    const unsigned short* __restrict__ resid,
    const short* __restrict__ Bt, float* __restrict__ C,
    const float* __restrict__ bias, int M, int Nn, int K)
{
    __shared__ short As[2][32 * 64];    // 8 KB
    __shared__ short Bs[2][64 * 64];    // 16 KB
    const int tid = threadIdx.x;
    const int w = tid >> 6, L = tid & 63;
    const int quad = L >> 4, lr = L & 15;
    const int row0 = blockIdx.x * 32;

    const int schunk = (L & 7) ^ (L >> 3);
    int ga = row0 + w * 8 + (L >> 3); if (ga > M - 1) ga = M - 1;
    int gbrow = w * 16 + (L >> 3);
    int gb0 = gbrow;     if (gb0 > Nn - 1) gb0 = Nn - 1;
    int gb1 = gbrow + 8; if (gb1 > Nn - 1) gb1 = Nn - 1;
    const float* xg = X + (size_t)ga * K + schunk * 8;
    const unsigned short* rg = resid + (size_t)ga * K + schunk * 8;
    const short* bgp0 = Bt + (size_t)gb0 * K + schunk * 8;
    const short* bgp1 = Bt + (size_t)gb1 * K + schunk * 8;

    floatx4 acc[2];
    const floatx4 zf = {0.f, 0.f, 0.f, 0.f};
    acc[0] = zf; acc[1] = zf;
    const float invN = 1.0f / NN;
    const int nt = K >> 6;   // 4

    floatx4 xa, xb2; ushort8v rv;
    xa  = *(const floatx4*)(xg);
    xb2 = *(const floatx4*)(xg + 4);
    rv  = *(const ushort8v*)(rg);
    gl2lds16(bgp0, &Bs[0][w * 1024]);
    gl2lds16(bgp1, &Bs[0][w * 1024 + 512]);
    {
        const int c = schunk * 8;
        short8 av;
        #pragma unroll
        for (int q = 0; q < 8; q++) {
            float m  = stats[c + q] * invN;
            float sq = stats[256 + c + q] * invN;
            float rs = rsqrtf(sq - m * m + 1e-5f) * g[c + q];
            float sh = be[c + q] - m * rs;
            float v = (q < 4 ? xa[q & 3] : xb2[q & 3]) * rs + sh;
            v = (v > 0.f) ? v : (expf(v) - 1.f);
            v += bf2f(rv[q]);
            av[q] = f2bf(v);
        }
        *(short8*)&As[0][w * 512 + L * 8] = av;
    }
    __syncthreads();
    int cur = 0;
    for (int t = 0; t < nt; t++) {
        floatx4 nxa, nxb2; ushort8v nrv;
        if (t + 1 < nt) {                    // issue next-tile loads before MFMA
            const int k0 = (t + 1) << 6;
            nxa  = *(const floatx4*)(xg + k0);
            nxb2 = *(const floatx4*)(xg + k0 + 4);
            nrv  = *(const ushort8v*)(rg + k0);
            gl2lds16(bgp0 + k0, &Bs[cur ^ 1][w * 1024]);
            gl2lds16(bgp1 + k0, &Bs[cur ^ 1][w * 1024 + 512]);
        }
        #pragma unroll
        for (int ks = 0; ks < 2; ks++) {
            const int sl = ((ks * 4 + quad) ^ (lr & 7)) * 8;
            short8 bfr = *(const short8*)&Bs[cur][(w * 16 + lr) * 64 + sl];
            #pragma unroll
            for (int i = 0; i < 2; i++) {
                short8 afr = *(const short8*)&As[cur][(i * 16 + lr) * 64 + sl];
                acc[i] = __builtin_amdgcn_mfma_f32_16x16x32_bf16(afr, bfr, acc[i], 0, 0, 0);
            }
        }
        if (t + 1 < nt) {                    // process next A-tile after MFMA
            const int c = schunk * 8 + ((t + 1) << 6);
            short8 av;
            #pragma unroll
            for (int q = 0; q < 8; q++) {
                float m  = stats[c + q] * invN;
                float sq = stats[256 + c + q] * invN;
                float rs = rsqrtf(sq - m * m + 1e-5f) * g[c + q];
                float sh = be[c + q] - m * rs;
                float v = (q < 4 ? nxa[q & 3] : nxb2[q & 3]) * rs + sh;
                v = (v > 0.f) ? v : (expf(v) - 1.f);
                v += bf2f(nrv[q]);
                av[q] = f2bf(v);
            }
            *(short8*)&As[cur ^ 1][w * 512 + L * 8] = av;
        }
        __syncthreads();
        cur ^= 1;
    }
    const int ccol = w * 16 + lr;
    if (ccol < Nn) {
        float bv = bias ? bias[ccol] : 0.f;
        #pragma unroll
        for (int i = 0; i < 2; i++) {
            #pragma unroll
            for (int r = 0; r < 4; r++) {
                int crow = row0 + i * 16 + quad * 4 + r;
                if (crow < M) C[(size_t)crow * Nn + ccol] = acc[i][r] + bv;
            }
        }
    }
}

// ---------------- prep: W0T/WcT transposes + edge counting ----------------
__global__ __launch_bounds__(256) void prep_a(
    const float* __restrict__ W0, const float* __restrict__ Wc,
    const int* __restrict__ edst, int E,
    short* __restrict__ W0T, short* __restrict__ WcT,
    int* __restrict__ counts)
{
    const int b = blockIdx.x, t = threadIdx.x;
    if (b < 256) {                  // W0T [256][256]
        W0T[b * 256 + t] = f2bf(W0[t * 256 + b]);
    } else if (b < 296) {           // WcT bf16 [40][256]
        int o = b - 256;
        WcT[o * 256 + t] = f2bf(Wc[t * 40 + o]);
    } else {                        // count edges
        int e = (b - 296) * 256 + t;
        if (e < E) atomicAdd(&counts[edst[e]], 1);
    }
}

// ---------------- CSR scan: 1024 thr, compile-time P=10, register-cached degs ----------
__global__ __launch_bounds__(1024) void scan_kernel(
    int* __restrict__ counts, int* __restrict__ offsets,
    int* __restrict__ cursor, int* __restrict__ elist)
{
    __shared__ int wsum[16];
    const int t = threadIdx.x, lane = t & 63, wid = t >> 6;
    constexpr int P = 10;            // NN/1024 rounded up; NN = 10000
    const int base = t * P;
    int deg[P], loc[P];
    int s = 0;
    #pragma unroll
    for (int j = 0; j < P; j++) {    // independent loads, all in flight
        int i = base + j;
        loc[j] = s;
        deg[j] = (i < NN) ? counts[i] + 1 : 0;   // +1 self-loop
        s += deg[j];
    }
    int inc = s;
    #pragma unroll
    for (int off = 1; off < 64; off <<= 1) {
        int tv = __shfl_up(inc, off, 64);
        if (lane >= off) inc += tv;
    }
    if (lane == 63) wsum[wid] = inc;
    __syncthreads();
    if (t < 16) {
        int v = wsum[t];
        int winc = v;
        #pragma unroll
        for (int off = 1; off < 16; off <<= 1) {
            int tv = __shfl_up(winc, off, 16);
            if (t >= off) winc += tv;
        }
        wsum[t] = winc - v;          // exclusive wave offset
    }
    __syncthreads();
    int excl = inc - s + wsum[wid];
    #pragma unroll
    for (int j = 0; j < P; j++) {
        int i = base + j;
        if (i < NN) {
            int o = excl + loc[j];
            counts[i] = deg[j];
            offsets[i] = o;
            elist[o] = i;            // self-loop in slot 0
            cursor[i] = o + 1;
        }
    }
}

// ---------------- fused softmax(no-max)+aggregate + BN-STATS, layer 0 ----------------
// BN stats fused: each block LDS-reduces its 4 nodes' column sums (reusing pw_s,
// dead after the gather), does ONE hierarchical atomic per column into 64 partial
// slots (~39 contenders/addr), and the LAST block (device-scope counter, no spin ->
// deadlock-free) collapses the 64x512 partials into stats0. Replaces the separate
// bn_stats kernel + its 10MB re-read + launch.
__global__ __launch_bounds__(256) void agg0_fused(
    const unsigned short* __restrict__ h0b, const float* __restrict__ s0,
    const int* __restrict__ offsets, const int* __restrict__ counts,
    const int* __restrict__ elist, float* __restrict__ out,
    float* __restrict__ pstats, unsigned int* __restrict__ donec,
    float* __restrict__ stats0)
{
    __shared__ float pw_s[4][CHK * 8];
    __shared__ int   sn_s[4][CHK];
    __shared__ int   lastBlk;
    const int wid = threadIdx.x >> 6, L = threadIdx.x & 63;
    const int n = blockIdx.x * 4 + wid;   // NN % 4 == 0
    float* pw = pw_s[wid];
    int*   sw = sn_s[wid];
    const int deg = counts[n], start = offsets[n];
    const int hL = L >> 3;

    floatx4 sda = *(const floatx4*)(s0 + n * 16 + 8);
    floatx4 sdb = *(const floatx4*)(s0 + n * 16 + 12);
    float sd[8] = {sda[0], sda[1], sda[2], sda[3], sdb[0], sdb[1], sdb[2], sdb[3]};
    float lp[8] = {0.f, 0.f, 0.f, 0.f, 0.f, 0.f, 0.f, 0.f};
    float a0 = 0.f, a1 = 0.f, a2 = 0.f, a3 = 0.f;

    for (int e0 = 0; e0 < deg; e0 += CHK) {
        int ch = deg - e0; if (ch > CHK) ch = CHK;
        if (L < ch) {
            int sn = elist[start + e0 + L];
            sw[L] = sn;
            floatx4 ssa = *(const floatx4*)(s0 + sn * 16);
            floatx4 ssb = *(const floatx4*)(s0 + sn * 16 + 4);
            float ss[8] = {ssa[0], ssa[1], ssa[2], ssa[3], ssb[0], ssb[1], ssb[2], ssb[3]};
            float p[8];
            #pragma unroll
            for (int h = 0; h < 8; h++) {
                float v = ss[h] + sd[h];
                v = (v > 0.f) ? v : 0.2f * v;
                p[h] = exp2f(v * LOG2E);
                lp[h] += p[h];
            }
            floatx4 p0 = {p[0], p[1], p[2], p[3]};
            floatx4 p1 = {p[4], p[5], p[6], p[7]};
            *(floatx4*)&pw[L * 8] = p0;
            *(floatx4*)&pw[L * 8 + 4] = p1;
        }
        int e = 0;
        for (; e + 4 <= ch; e += 4) {          // 4-edge unroll
            float wA = pw[e * 8 + hL];
            float wB = pw[e * 8 + 8 + hL];
            float wC = pw[e * 8 + 16 + hL];
            float wD = pw[e * 8 + 24 + hL];
            ushort4 vA = *(const ushort4*)(h0b + (size_t)sw[e] * 256 + 4 * L);
            ushort4 vB = *(const ushort4*)(h0b + (size_t)sw[e + 1] * 256 + 4 * L);
            ushort4 vC = *(const ushort4*)(h0b + (size_t)sw[e + 2] * 256 + 4 * L);
            ushort4 vD = *(const ushort4*)(h0b + (size_t)sw[e + 3] * 256 + 4 * L);
            a0 += wA * bf2f(vA.x); a1 += wA * bf2f(vA.y);
            a2 += wA * bf2f(vA.z); a3 += wA * bf2f(vA.w);
            a0 += wB * bf2f(vB.x); a1 += wB * bf2f(vB.y);
            a2 += wB * bf2f(vB.z); a3 += wB * bf2f(vB.w);
            a0 += wC * bf2f(vC.x); a1 += wC * bf2f(vC.y);
            a2 += wC * bf2f(vC.z); a3 += wC * bf2f(vC.w);
            a0 += wD * bf2f(vD.x); a1 += wD * bf2f(vD.y);
            a2 += wD * bf2f(vD.z); a3 += wD * bf2f(vD.w);
        }
        for (; e + 2 <= ch; e += 2) {
            float wA = pw[e * 8 + hL];
            float wB = pw[e * 8 + 8 + hL];
            ushort4 vA = *(const ushort4*)(h0b + (size_t)sw[e] * 256 + 4 * L);
            ushort4 vB = *(const ushort4*)(h0b + (size_t)sw[e + 1] * 256 + 4 * L);
            a0 += wA * bf2f(vA.x); a1 += wA * bf2f(vA.y);
            a2 += wA * bf2f(vA.z); a3 += wA * bf2f(vA.w);
            a0 += wB * bf2f(vB.x); a1 += wB * bf2f(vB.y);
            a2 += wB * bf2f(vB.z); a3 += wB * bf2f(vB.w);
        }
        if (e < ch) {
            float wA = pw[e * 8 + hL];
            ushort4 vA = *(const ushort4*)(h0b + (size_t)sw[e] * 256 + 4 * L);
            a0 += wA * bf2f(vA.x); a1 += wA * bf2f(vA.y);
            a2 += wA * bf2f(vA.z); a3 += wA * bf2f(vA.w);
        }
    }
    #pragma unroll
    for (int off = 1; off < 64; off <<= 1)
        #pragma unroll
        for (int h = 0; h < 8; h++)
            lp[h] += __shfl_xor(lp[h], off, 64);
    float inv = 1.f / lp[hL];
    floatx4 o = {a0 * inv, a1 * inv, a2 * inv, a3 * inv};
    *(floatx4*)(out + (size_t)n * 256 + 4 * L) = o;

    // ---- fused BN-stats: block-level column sums -> 64-slot hierarchical atomics ----
    #pragma unroll
    for (int k = 0; k < 4; k++) {
        pw[4 * L + k] = o[k];                 // s   (wave-local row; pw dead now)
        pw[256 + 4 * L + k] = o[k] * o[k];    // s2
    }
    __syncthreads();
    {
        const int t = threadIdx.x;            // 0..255 -> column t
        float ps  = pw_s[0][t] + pw_s[1][t] + pw_s[2][t] + pw_s[3][t];
        float ps2 = pw_s[0][256 + t] + pw_s[1][256 + t] + pw_s[2][256 + t] + pw_s[3][256 + t];
        const int slot = (int)(blockIdx.x & 63);
        atomicAdd(&pstats[slot * 512 + t], ps);
        atomicAdd(&pstats[slot * 512 + 256 + t], ps2);
        __threadfence();                      // drain this thread's atomics
        __syncthreads();                      // all threads' atomics drained
        if (t == 0)
            lastBlk = (atomicAdd(donec, 1u) == (unsigned)(gridDim.x - 1));
        __syncthreads();
        if (lastBlk) {                        // last block reduces (no spin)
            __threadfence();                  // acquire: see all partials
            float s = 0.f, s2v = 0.f;
            #pragma unroll
            for (int k = 0; k < 64; k++) {
                s   += pstats[k * 512 + t];
                s2v += pstats[k * 512 + 256 + t];
            }
            stats0[t] = s;
            stats0[256 + t] = s2v;
        }
    }
}

// ---------------- layer-1 aggregate: ONE wave per node (all 8 heads), 4-edge unroll ----
__global__ __launch_bounds__(256) void agg1_full(
    const unsigned short* __restrict__ hb, const float* __restrict__ s1,
    const int* __restrict__ offsets, const int* __restrict__ counts,
    const int* __restrict__ elist, short* __restrict__ aggout)
{
    __shared__ float pw_s[4][CHK * 8];
    __shared__ int   sn_s[4][CHK];
    const int wid = threadIdx.x >> 6, L = threadIdx.x & 63;
    const int n = blockIdx.x * 4 + wid;   // NN % 4 == 0
    float* pw = pw_s[wid];
    int*   sw = sn_s[wid];
    const int deg = counts[n], start = offsets[n];

    floatx4 sda = *(const floatx4*)(s1 + n * 16 + 8);
    floatx4 sdb = *(const floatx4*)(s1 + n * 16 + 12);
    float sd[8] = {sda[0], sda[1], sda[2], sda[3], sdb[0], sdb[1], sdb[2], sdb[3]};
    float lp[8] = {0.f, 0.f, 0.f, 0.f, 0.f, 0.f, 0.f, 0.f};
    float acc[8][4];
    #pragma unroll
    for (int h = 0; h < 8; h++)
        #pragma unroll
        for (int f = 0; f < 4; f++) acc[h][f] = 0.f;

    for (int e0 = 0; e0 < deg; e0 += CHK) {
        int ch = deg - e0; if (ch > CHK) ch = CHK;
        if (L < ch) {
            int sn = elist[start + e0 + L];
            sw[L] = sn;
            floatx4 ssa = *(const floatx4*)(s1 + sn * 16);
            floatx4 ssb = *(const floatx4*)(s1 + sn * 16 + 4);
            float ss[8] = {ssa[0], ssa[1], ssa[2], ssa[3], ssb[0], ssb[1], ssb[2], ssb[3]};
            float p[8];
            #pragma unroll
            for (int h = 0; h < 8; h++) {
                float v = ss[h] + sd[h];
                v = (v > 0.f) ? v : 0.2f * v;
                p[h] = exp2f(v * LOG2E);
                lp[h] += p[h];
            }
            floatx4 p0 = {p[0], p[1], p[2], p[3]};
            floatx4 p1 = {p[4], p[5], p[6], p[7]};
            *(floatx4*)&pw[L * 8] = p0;
            *(floatx4*)&pw[L * 8 + 4] = p1;
        }
        int e = 0;
        for (; e + 4 <= ch; e += 4) {          // 4-edge unroll
            ushort4 vA = *(const ushort4*)(hb + (size_t)sw[e] * 256 + 4 * L);
            ushort4 vB = *(const ushort4*)(hb + (size_t)sw[e + 1] * 256 + 4 * L);
            ushort4 vC = *(const ushort4*)(hb + (size_t)sw[e + 2] * 256 + 4 * L);
            ushort4 vD = *(const ushort4*)(hb + (size_t)sw[e + 3] * 256 + 4 * L);
            floatx4 p0A = *(const floatx4*)&pw[e * 8];
            floatx4 p1A = *(const floatx4*)&pw[e * 8 + 4];
            floatx4 p0B = *(const floatx4*)&pw[e * 8 + 8];
            floatx4 p1B = *(const floatx4*)&pw[e * 8 + 12];
            floatx4 p0C = *(const floatx4*)&pw[e * 8 + 16];
            floatx4 p1C = *(const floatx4*)&pw[e * 8 + 20];
            floatx4 p0D = *(const floatx4*)&pw[e * 8 + 24];
            floatx4 p1D = *(const floatx4*)&pw[e * 8 + 28];
            float a0 = bf2f(vA.x), a1 = bf2f(vA.y), a2 = bf2f(vA.z), a3 = bf2f(vA.w);
            #pragma unroll
            for (int h = 0; h < 4; h++) {
                acc[h][0] += p0A[h] * a0;     acc[h][1] += p0A[h] * a1;
                acc[h][2] += p0A[h] * a2;     acc[h][3] += p0A[h] * a3;
                acc[h + 4][0] += p1A[h] * a0; acc[h + 4][1] += p1A[h] * a1;
                acc[h + 4][2] += p1A[h] * a2; acc[h + 4][3] += p1A[h] * a3;
            }
            float b0 = bf2f(vB.x), b1 = bf2f(vB.y), b2 = bf2f(vB.z), b3 = bf2f(vB.w);
            #pragma unroll
            for (int h = 0; h < 4; h++) {
                acc[h][0] += p0B[h] * b0;     acc[h][1] += p0B[h] * b1;
                acc[h][2] += p0B[h] * b2;     acc[h][3] += p0B[h] * b3;
                acc[h + 4][0] += p1B[h] * b0; acc[h + 4][1] += p1B[h] * b1;
                acc[h + 4][2] += p1B[h] * b2; acc[h + 4][3] += p1B[h] * b3;
            }
            float c0 = bf2f(vC.x), c1 = bf2f(vC.y), c2 = bf2f(vC.z), c3 = bf2f(vC.w);
            #pragma unroll
            for (int h = 0; h < 4; h++) {
                acc[h][0] += p0C[h] * c0;     acc[h][1] += p0C[h] * c1;
                acc[h][2] += p0C[h] * c2;     acc[h][3] += p0C[h] * c3;
                acc[h + 4][0] += p1C[h] * c0; acc[h + 4][1] += p1C[h] * c1;
                acc[h + 4][2] += p1C[h] * c2; acc[h + 4][3] += p1C[h] * c3;
            }
            float d0 = bf2f(vD.x), d1 = bf2f(vD.y), d2 = bf2f(vD.z), d3 = bf2f(vD.w);
            #pragma unroll
            for (int h = 0; h < 4; h++) {
                acc[h][0] += p0D[h] * d0;     acc[h][1] += p0D[h] * d1;
                acc[h][2] += p0D[h] * d2;     acc[h][3] += p0D[h] * d3;
                acc[h + 4][0] += p1D[h] * d0; acc[h + 4][1] += p1D[h] * d1;
                acc[h + 4][2] += p1D[h] * d2; acc[h + 4][3] += p1D[h] * d3;
            }
        }
        for (; e + 2 <= ch; e += 2) {
            floatx4 p0A = *(const floatx4*)&pw[e * 8];
            floatx4 p1A = *(const floatx4*)&pw[e * 8 + 4];
            floatx4 p0B = *(const floatx4*)&pw[e * 8 + 8];
            floatx4 p1B = *(const floatx4*)&pw[e * 8 + 12];
            ushort4 vA = *(const ushort4*)(hb + (size_t)sw[e] * 256 + 4 * L);
            ushort4 vB = *(const ushort4*)(hb + (size_t)sw[e + 1] * 256 + 4 * L);
            float a0 = bf2f(vA.x), a1 = bf2f(vA.y), a2 = bf2f(vA.z), a3 = bf2f(vA.w);
            float b0 = bf2f(vB.x), b1 = bf2f(vB.y), b2 = bf2f(vB.z), b3 = bf2f(vB.w);
            #pragma unroll
            for (int h = 0; h < 4; h++) {
                acc[h][0] += p0A[h] * a0;     acc[h][1] += p0A[h] * a1;
                acc[h][2] += p0A[h] * a2;     acc[h][3] += p0A[h] * a3;
                acc[h + 4][0] += p1A[h] * a0; acc[h + 4][1] += p1A[h] * a1;
                acc[h + 4][2] += p1A[h] * a2; acc[h + 4][3] += p1A[h] * a3;
            }
            #pragma unroll
            for (int h = 0; h < 4; h++) {
                acc[h][0] += p0B[h] * b0;     acc[h][1] += p0B[h] * b1;
                acc[h][2] += p0B[h] * b2;     acc[h][3] += p0B[h] * b3;
                acc[h + 4][0] += p1B[h] * b0; acc[h + 4][1] += p1B[h] * b1;
                acc[h + 4][2] += p1B[h] * b2; acc[h + 4][3] += p1B[h] * b3;
            }
        }
        if (e < ch) {
            floatx4 p0A = *(const floatx4*)&pw[e * 8];
            floatx4 p1A = *(const floatx4*)&pw[e * 8 + 4];
            ushort4 vA = *(const ushort4*)(hb + (size_t)sw[e] * 256 + 4 * L);
            float a0 = bf2f(vA.x), a1 = bf2f(vA.y), a2 = bf2f(vA.z), a3 = bf2f(vA.w);
            #pragma unroll
            for (int h = 0; h < 4; h++) {
                acc[h][0] += p0A[h] * a0;     acc[h][1] += p0A[h] * a1;
                acc[h][2] += p0A[h] * a2;     acc[h][3] += p0A[h] * a3;
                acc[h + 4][0] += p1A[h] * a0; acc[h + 4][1] += p1A[h] * a1;
                acc[h + 4][2] += p1A[h] * a2; acc[h + 4][3] += p1A[h] * a3;
            }
        }
    }
    #pragma unroll
    for (int off = 1; off < 64; off <<= 1)
        #pragma unroll
        for (int h = 0; h < 8; h++)
            lp[h] += __shfl_xor(lp[h], off, 64);
    #pragma unroll
    for (int h = 0; h < 8; h++) {
        float inv = 1.f / lp[h];
        short4 o = {f2bf(acc[h][0] * inv), f2bf(acc[h][1] * inv),
                    f2bf(acc[h][2] * inv), f2bf(acc[h][3] * inv)};
        *(short4*)(aggout + (size_t)n * 2048 + h * 256 + 4 * L) = o;
    }
}

// ---------------- BN + ELU + bf16 write + layer-1 score, one block per node ----------------
__global__ __launch_bounds__(256) void bnapply_score1(
    const float* __restrict__ xg, const float* __restrict__ stats,
    const float* __restrict__ g, const float* __restrict__ be,
    const float* __restrict__ v1, short* __restrict__ hactb, float* __restrict__ s1)
{
    __shared__ float row[256];
    __shared__ float part[16][17];
    const int n = blockIdx.x, t = threadIdx.x;
    const float invN = 1.0f / NN;
    float mu = stats[t] * invN;
    float var = stats[256 + t] * invN - mu * mu;
    float v = g[t] * (xg[(size_t)n * 256 + t] - mu) * rsqrtf(var + 1e-5f) + be[t];
    v = (v > 0.f) ? v : (expf(v) - 1.f);   // ELU
    hactb[(size_t)n * 256 + t] = f2bf(v);
    row[t] = v;
    __syncthreads();
    int j = t & 15, f0 = t >> 4;
    float p = 0.f;
    #pragma unroll
    for (int k = 0; k < 16; k++)
        p += row[f0 * 16 + k] * v1[(f0 * 16 + k) * 16 + j];
    part[f0][j] = p;
    __syncthreads();
    if (t < 16) {
        float s = 0.f;
        #pragma unroll
        for (int k = 0; k < 16; k++) s += part[k][t];
        s1[n * 16 + t] = s;
    }
}

// ---------------- launch ----------------
extern "C" void kernel_launch(void* const* d_in, const int* in_sizes, int n_in,
                              void* d_out, int out_size, void* d_ws, size_t ws_size,
                              hipStream_t stream) {
    const float* x      = (const float*)d_in[0];
    const int*   eidx   = (const int*)d_in[1];
    const float* W0     = (const float*)d_in[2];
    const float* a_src0 = (const float*)d_in[3];
    const float* a_dst0 = (const float*)d_in[4];
    const float* g0     = (const float*)d_in[6];
    const float* be0    = (const float*)d_in[7];
    const float* W1     = (const float*)d_in[8];
    const float* a_src1 = (const float*)d_in[9];
    const float* a_dst1 = (const float*)d_in[10];
    const float* g1     = (const float*)d_in[12];
    const float* be1    = (const float*)d_in[13];
    const float* Wc     = (const float*)d_in[14];
    const float* bc     = (const float*)d_in[15];
    float* out = (float*)d_out;

    const int E = in_sizes[1] / 2;
    const int* esrc = eidx;
    const int* edst = eidx + E;

    char* ws = (char*)d_ws;
    size_t off = 0;
    auto alloc = [&](size_t bytes) {
        void* p = ws + off;
        off += (bytes + 255) & ~(size_t)255;
        return p;
    };
    // stats + pstats + donec + counts contiguous -> single memset
    float* stats   = (float*)alloc(1024 * 4);          // stats0 | stats1
    float* pstats  = (float*)alloc(64 * 512 * 4);      // 128 KB BN partials
    unsigned int* donec = (unsigned int*)alloc(256);   // last-block counter
    int*   counts  = (int*)alloc(NN * 4);
    float* out1    = (float*)alloc((size_t)NN * 256 * 4);
    short* h0b     = (short*)alloc((size_t)NN * 256 * 2);
    float* s0      = (float*)alloc((size_t)NN * 16 * 4);
    float* s1      = (float*)alloc((size_t)NN * 16 * 4);
    float* v1      = (float*)alloc(4096 * 4);
    float* h_gat0  = (float*)alloc((size_t)NN * 256 * 4);
    short* hactb   = (short*)alloc((size_t)NN * 256 * 2);
    short* agg1bf  = (short*)alloc((size_t)NN * 2048 * 2);
    short* W0T     = (short*)alloc((size_t)256 * 256 * 2);
    short* W1pT    = (short*)alloc((size_t)256 * 2048 * 2);
    short* WcT     = (short*)alloc((size_t)64 * 256 * 2);
    int* offsets   = (int*)alloc((NN + 16) * 4);
    int* cursor    = (int*)alloc(NN * 4);
    int* elist     = (int*)alloc((size_t)(E + NN) * 4);

    float* stats0 = stats;
    float* stats1 = stats + 512;

    hipMemsetAsync(stats, 0, 1024 * 4 + 64 * 512 * 4 + 256 + NN * 4, stream);

    const int cntBlocks = (E + 255) / 256;

    // prep: W0T/WcT + edge counting (x cast is fused into gemm0's A-staging)
    prep_a<<<296 + cntBlocks, 256, 0, stream>>>(W0, Wc, edst, E, W0T, WcT, counts);

    // CSR scan (1024 threads, register-cached, ~4us)
    scan_kernel<<<1, 1024, 0, stream>>>(counts, offsets, cursor, elist);

    const int gy = (NN + 63) / 64;           // 157
    const int gB = 16 * ((gy + 7) / 8);      // 320 (XCD-paired swizzle groups)

    // layer-0 GEMM (f32 A + fused cast + fused scores) + scatter/v1/W1pT tails
    gemm_bf16_w128<<<gB + cntBlocks + 528, 256, 0, stream>>>(
        x, W0T, h0b,
        a_src0, a_dst0, s0,
        esrc, edst, cursor, elist, E, cntBlocks,
        W1, a_src1, a_dst1, v1, W1pT,
        gB, gy, NN, 256, 256, 1.0f);

    // agg0 with FUSED BN-stats (last block reduces into stats0; bn_stats kernel gone)
    agg0_fused<<<NN / 4, 256, 0, stream>>>(
        (const unsigned short*)h0b, s0, offsets, counts, elist, h_gat0,
        pstats, donec, stats0);
    bnapply_score1<<<NN, 256, 0, stream>>>(h_gat0, stats0, g0, be0, v1, hactb, s1);

    // layer 1 (BM=32 double-buffered GEMM: 626 live blocks -> 2.45/CU co-resident)
    agg1_full<<<NN / 4, 256, 0, stream>>>(
        (const unsigned short*)hactb, s1, offsets, counts, elist, agg1bf);
    const int gy1 = (NN + 31) / 32;          // 313
    const int gB1 = 16 * ((gy1 + 7) / 8);    // 640
    gemm1_db<<<gB1, 256, 0, stream>>>(
        agg1bf, W1pT, out1, stats1, gy1, NN, 256, 2048, 0.125f);

    // classifier with fused BN+ELU+residual A-staging (BM=32 -> 313 blocks, 2-phase)
    classifier_fused<<<(NN + 31) / 32, 256, 0, stream>>>(
        out1, stats1, g1, be1, (const unsigned short*)hactb,
        WcT, out, bc, NN, NCLS, 256);
}

// Round 13
// 243.617 us; speedup vs baseline: 1.7554x; 1.7554x over previous
//
#include <hip/hip_runtime.h>
#include <math.h>

#define NN 10000
#define HEADS 8
#define NCLS 40
#define CHK 64
#define LOG2E 1.4426950408889634f

typedef __attribute__((ext_vector_type(8))) short short8;
typedef __attribute__((ext_vector_type(8))) unsigned short ushort8v;
typedef __attribute__((ext_vector_type(4))) float floatx4;

static __device__ __forceinline__ short f2bf(float f) {
    unsigned u = __builtin_bit_cast(unsigned, f);
    unsigned r = (u + 0x7fff + ((u >> 16) & 1)) >> 16;
    return (short)r;
}
static __device__ __forceinline__ float bf2f(unsigned short u) {
    unsigned x = ((unsigned)u) << 16;
    return __builtin_bit_cast(float, x);
}
static __device__ __forceinline__ void gl2lds16(const void* g, void* l) {
    __builtin_amdgcn_global_load_lds(
        (const __attribute__((address_space(1))) unsigned int*)g,
        (__attribute__((address_space(3))) unsigned int*)l, 16, 0, 0);
}

// ---------------- layer-0 GEMM: BM=64, BN=128, BK=64, SINGLE-buffer (24 KB) ----------
// Single-buffer kept here on purpose: this launch carries latency-bound tail blocks
// (scatter atomics, W1 prep) that want max blocks/CU (r6 post-mortem). K=256 -> only
// 4 barrier-drains, so pipelining matters little for the GEMM blocks themselves.
// A is staged from f32 with fused bf16 cast (reg->ds_write, byte-identical layout
// to gl2lds16). Fused epilogue: per-head scores (head fully inside one wave).
__global__ __launch_bounds__(256) void gemm_bf16_w128(
    const float* __restrict__ Af32, const short* __restrict__ Bt,
    short* __restrict__ Cbf,
    const float* __restrict__ asrc, const float* __restrict__ adst,
    float* __restrict__ s0,
    const int* __restrict__ esrc, const int* __restrict__ edst,
    int* __restrict__ cursor, int* __restrict__ elist, int E, int scatBlocks,
    const float* __restrict__ W1, const float* __restrict__ a_src1,
    const float* __restrict__ a_dst1, float* __restrict__ v1,
    short* __restrict__ W1pT,
    int gemmBlocks, int gridY,
    int M, int Nn, int K, float alpha)
{
    __shared__ short As[64 * 64];    // 8 KB (aliased as f32 transpose tile in tails)
    __shared__ short Bs[128 * 64];   // 16 KB
    const int tid = threadIdx.x;
    if ((int)blockIdx.x >= gemmBlocks) {
        int td = (int)blockIdx.x - gemmBlocks;
        if (td < scatBlocks) {               // CSR edge scatter
            int e = td * 256 + tid;
            if (e < E) {
                int dn = edst[e];
                int pos = atomicAdd(&cursor[dn], 1);
                elist[pos] = esrc[e];
            }
            return;
        }
        td -= scatBlocks;
        if (td < 16) {                       // v1 = folded W1·a  [256 f][16 j]
            int idx = td * 256 + tid;
            int f = idx >> 4, j = idx & 15;
            int h = j & 7;
            const float* a = (j < 8) ? a_src1 : a_dst1;
            float s = 0.f;
            for (int c = 0; c < 256; c++)
                s += W1[f * 2048 + h * 256 + c] * a[h * 256 + c];
            v1[idx] = s;
            return;
        }
        td -= 16;
        {                                    // W1pT bf16 [256 c][2048 hf], td in [0,512)
            float (*tile)[33] = (float(*)[33])As;
            int h = td >> 6, f0 = ((td >> 3) & 7) * 32, c0 = (td & 7) * 32;
            int tx = tid & 31, ty = tid >> 5;
            for (int r = ty; r < 32; r += 8)
                tile[r][tx] = W1[(size_t)(f0 + r) * 2048 + h * 256 + c0 + tx];
            __syncthreads();
            for (int r = ty; r < 32; r += 8)
                W1pT[(size_t)(c0 + r) * 2048 + h * 256 + f0 + tx] = f2bf(tile[tx][r]);
            return;
        }
    }
    const int w = tid >> 6, L = tid & 63;
    const int quad = L >> 4, lr = L & 15;
    const int d = blockIdx.x;
    const int by = (d >> 4) * 8 + (d & 7);   // pair (bx=0,by),(bx=1,by) differ by 8 -> same XCD
    const int bx = (d >> 3) & 1;
    if (by >= gridY) return;
    const int col0 = bx * 128, row0 = by * 64;

    const int schunk = (L & 7) ^ (L >> 3);   // (row&7)==(L>>3) for all staged rows
    const int sarow = w * 16 + (L >> 3);
    int ga0 = row0 + sarow;     if (ga0 > M - 1) ga0 = M - 1;
    int ga1 = row0 + sarow + 8; if (ga1 > M - 1) ga1 = M - 1;
    const float* axp0 = Af32 + (size_t)ga0 * K + schunk * 8;
    const float* axp1 = Af32 + (size_t)ga1 * K + schunk * 8;
    short* alw0 = &As[w * 1024 + L * 8];     // == gl2lds16 dest: base + L*16 bytes
    short* alw1 = &As[w * 1024 + 512 + L * 8];
    const int sbrow = w * 32 + (L >> 3);
    int gb[4];
    #pragma unroll
    for (int c = 0; c < 4; c++) {
        gb[c] = col0 + sbrow + c * 8;
        if (gb[c] > Nn - 1) gb[c] = Nn - 1;
    }
    const short* bgp0 = Bt + (size_t)gb[0] * K + schunk * 8;
    const short* bgp1 = Bt + (size_t)gb[1] * K + schunk * 8;
    const short* bgp2 = Bt + (size_t)gb[2] * K + schunk * 8;
    const short* bgp3 = Bt + (size_t)gb[3] * K + schunk * 8;
    short* blp0 = &Bs[w * 2048];
    short* blp1 = &Bs[w * 2048 + 512];
    short* blp2 = &Bs[w * 2048 + 1024];
    short* blp3 = &Bs[w * 2048 + 1536];

    floatx4 acc[4][2];
    const floatx4 zf = {0.f, 0.f, 0.f, 0.f};
    #pragma unroll
    for (int i = 0; i < 4; i++)
        #pragma unroll
        for (int j = 0; j < 2; j++) acc[i][j] = zf;

    for (int k0 = 0; k0 < K; k0 += 64) {
        gl2lds16(bgp0 + k0, blp0);           // B DMA first: flies under A cast
        gl2lds16(bgp1 + k0, blp1);
        gl2lds16(bgp2 + k0, blp2);
        gl2lds16(bgp3 + k0, blp3);
        {                                    // f32 A, fused bf16 cast
            floatx4 va0 = *(const floatx4*)(axp0 + k0);
            floatx4 va1 = *(const floatx4*)(axp0 + k0 + 4);
            floatx4 vb0 = *(const floatx4*)(axp1 + k0);
            floatx4 vb1 = *(const floatx4*)(axp1 + k0 + 4);
            short8 o0, o1;
            #pragma unroll
            for (int q = 0; q < 8; q++) {
                o0[q] = f2bf(q < 4 ? va0[q & 3] : va1[q & 3]);
                o1[q] = f2bf(q < 4 ? vb0[q & 3] : vb1[q & 3]);
            }
            *(short8*)alw0 = o0;
            *(short8*)alw1 = o1;
        }
        __syncthreads();
        #pragma unroll
        for (int ks = 0; ks < 2; ks++) {
            const int sl = ((ks * 4 + quad) ^ (lr & 7)) * 8;
            short8 bfr[2];
            #pragma unroll
            for (int j = 0; j < 2; j++)
                bfr[j] = *(const short8*)&Bs[(w * 32 + j * 16 + lr) * 64 + sl];
            #pragma unroll
            for (int i = 0; i < 4; i++) {
                short8 afr = *(const short8*)&As[(i * 16 + lr) * 64 + sl];
                #pragma unroll
                for (int j = 0; j < 2; j++)
                    acc[i][j] = __builtin_amdgcn_mfma_f32_16x16x32_bf16(afr, bfr[j], acc[i][j], 0, 0, 0);
            }
        }
        __syncthreads();
    }
    #pragma unroll
    for (int j = 0; j < 2; j++) {
        int ccol = col0 + w * 32 + j * 16 + lr;
        if (ccol >= Nn) continue;
        #pragma unroll
        for (int i = 0; i < 4; i++) {
            #pragma unroll
            for (int r = 0; r < 4; r++) {
                int crow = row0 + i * 16 + quad * 4 + r;
                if (crow < M)
                    Cbf[(size_t)crow * Nn + ccol] = f2bf(alpha * acc[i][j][r]);
            }
        }
    }
    {          // fused layer-0 per-head scores from f32 acc (head fully inside wave)
        const int head = bx * 4 + w;
        float as0 = asrc[col0 + w * 32 + lr];
        float as1 = asrc[col0 + w * 32 + 16 + lr];
        float ad0 = adst[col0 + w * 32 + lr];
        float ad1 = adst[col0 + w * 32 + 16 + lr];
        #pragma unroll
        for (int i = 0; i < 4; i++) {
            #pragma unroll
            for (int r = 0; r < 4; r++) {
                float ps = acc[i][0][r] * as0 + acc[i][1][r] * as1;
                float pd = acc[i][0][r] * ad0 + acc[i][1][r] * ad1;
                #pragma unroll
                for (int off = 1; off < 16; off <<= 1) {
                    ps += __shfl_xor(ps, off, 64);
                    pd += __shfl_xor(pd, off, 64);
                }
                if (lr == 0) {
                    int crow = row0 + i * 16 + quad * 4 + r;
                    if (crow < M) {
                        s0[crow * 16 + head] = alpha * ps;
                        s0[crow * 16 + 8 + head] = alpha * pd;
                    }
                }
            }
        }
    }
}

// ---------------- layer-1 GEMM: BM=32, BN=128, BK=64, 2-phase double-buffer ----------
// 626 live blocks (2.45/CU co-resident at 40 KB LDS): inter-block TLP hides the
// per-iteration barrier stall the prefetch alone can't (r9/r10 post-mortem).
__global__ __launch_bounds__(256) void gemm1_db(
    const short* __restrict__ A, const short* __restrict__ Bt,
    float* __restrict__ C, float* __restrict__ stats,
    int gridY, int M, int Nn, int K, float alpha)
{
    __shared__ short As[2][32 * 64];     // 8 KB
    __shared__ short Bs[2][128 * 64];    // 32 KB
    const int tid = threadIdx.x;
    const int w = tid >> 6, L = tid & 63;
    const int quad = L >> 4, lr = L & 15;
    const int d = blockIdx.x;
    const int by = (d >> 4) * 8 + (d & 7);   // pair (bx=0,by),(bx=1,by) differ by 8 -> same XCD
    const int bx = (d >> 3) & 1;
    if (by >= gridY) return;
    const int col0 = bx * 128, row0 = by * 32;

    const int schunk = (L & 7) ^ (L >> 3);
    int ga = row0 + w * 8 + (L >> 3); if (ga > M - 1) ga = M - 1;
    const short* agp = A + (size_t)ga * K + schunk * 8;
    const int sbrow = w * 32 + (L >> 3);
    int gb[4];
    #pragma unroll
    for (int c = 0; c < 4; c++) {
        gb[c] = col0 + sbrow + c * 8;
        if (gb[c] > Nn - 1) gb[c] = Nn - 1;
    }
    const short* bgp0 = Bt + (size_t)gb[0] * K + schunk * 8;
    const short* bgp1 = Bt + (size_t)gb[1] * K + schunk * 8;
    const short* bgp2 = Bt + (size_t)gb[2] * K + schunk * 8;
    const short* bgp3 = Bt + (size_t)gb[3] * K + schunk * 8;

    floatx4 acc[2][2];
    const floatx4 zf = {0.f, 0.f, 0.f, 0.f};
    #pragma unroll
    for (int i = 0; i < 2; i++)
        #pragma unroll
        for (int j = 0; j < 2; j++) acc[i][j] = zf;

    const int nt = K >> 6;
    gl2lds16(agp,  &As[0][w * 512]);
    gl2lds16(bgp0, &Bs[0][w * 2048]);
    gl2lds16(bgp1, &Bs[0][w * 2048 + 512]);
    gl2lds16(bgp2, &Bs[0][w * 2048 + 1024]);
    gl2lds16(bgp3, &Bs[0][w * 2048 + 1536]);
    __syncthreads();
    int cur = 0;
    for (int t = 0; t < nt; t++) {
        if (t + 1 < nt) {                    // prefetch next tile into other buffer
            const int k0 = (t + 1) << 6;
            const int nb = cur ^ 1;
            gl2lds16(agp + k0,  &As[nb][w * 512]);
            gl2lds16(bgp0 + k0, &Bs[nb][w * 2048]);
            gl2lds16(bgp1 + k0, &Bs[nb][w * 2048 + 512]);
            gl2lds16(bgp2 + k0, &Bs[nb][w * 2048 + 1024]);
            gl2lds16(bgp3 + k0, &Bs[nb][w * 2048 + 1536]);
        }
        #pragma unroll
        for (int ks = 0; ks < 2; ks++) {
            const int sl = ((ks * 4 + quad) ^ (lr & 7)) * 8;
            short8 bfr[2];
            #pragma unroll
            for (int j = 0; j < 2; j++)
                bfr[j] = *(const short8*)&Bs[cur][(w * 32 + j * 16 + lr) * 64 + sl];
            #pragma unroll
            for (int i = 0; i < 2; i++) {
                short8 afr = *(const short8*)&As[cur][(i * 16 + lr) * 64 + sl];
                #pragma unroll
                for (int j = 0; j < 2; j++)
                    acc[i][j] = __builtin_amdgcn_mfma_f32_16x16x32_bf16(afr, bfr[j], acc[i][j], 0, 0, 0);
            }
        }
        __syncthreads();                     // prefetch landed + ds_reads done
        cur ^= 1;
    }
    float s[2] = {0.f, 0.f}, s2[2] = {0.f, 0.f};
    #pragma unroll
    for (int j = 0; j < 2; j++) {
        int ccol = col0 + w * 32 + j * 16 + lr;
        if (ccol >= Nn) continue;
        #pragma unroll
        for (int i = 0; i < 2; i++) {
            #pragma unroll
            for (int r = 0; r < 4; r++) {
                int crow = row0 + i * 16 + quad * 4 + r;
                if (crow < M) {
                    float v = alpha * acc[i][j][r];
                    C[(size_t)crow * Nn + ccol] = v;
                    s[j] += v; s2[j] += v * v;
                }
            }
        }
    }
    #pragma unroll
    for (int j = 0; j < 2; j++) {
        s[j]  += __shfl_xor(s[j], 16, 64);  s[j]  += __shfl_xor(s[j], 32, 64);
        s2[j] += __shfl_xor(s2[j], 16, 64); s2[j] += __shfl_xor(s2[j], 32, 64);
    }
    if (L < 16) {
        #pragma unroll
        for (int j = 0; j < 2; j++) {
            int ccol = col0 + w * 32 + j * 16 + L;
            if (ccol < Nn) {
                atomicAdd(&stats[ccol], s[j]);
                atomicAdd(&stats[256 + ccol], s2[j]);
            }
        }
    }
}

// ---------------- classifier GEMM, BM=32, 2-phase pipelined, fused BN+ELU+residual -----
__global__ __launch_bounds__(256) void classifier_fused(
    const float* __restrict__ X, const float* __restrict__ stats,
    const float* __restrict__ g, const float* __restrict__ be,
    const unsigned short* __restrict__ resid,
    const short* __restrict__ Bt, float* __restrict__ C,
    const float* __restrict__ bias, int M, int Nn, int K)
{
    __shared__ short As[2][32 * 64];    // 8 KB
    __shared__ short Bs[2][64 * 64];    // 16 KB
    const int tid = threadIdx.x;
    const int w = tid >> 6, L = tid & 63;
    const int quad = L >> 4, lr = L & 15;
    const int row0 = blockIdx.x * 32;

    const int schunk = (L & 7) ^ (L >> 3);
    int ga = row0 + w * 8 + (L >> 3); if (ga > M - 1) ga = M - 1;
    int gbrow = w * 16 + (L >> 3);
    int gb0 = gbrow;     if (gb0 > Nn - 1) gb0 = Nn - 1;
    int gb1 = gbrow + 8; if (gb1 > Nn - 1) gb1 = Nn - 1;
    const float* xg = X + (size_t)ga * K + schunk * 8;
    const unsigned short* rg = resid + (size_t)ga * K + schunk * 8;
    const short* bgp0 = Bt + (size_t)gb0 * K + schunk * 8;
    const short* bgp1 = Bt + (size_t)gb1 * K + schunk * 8;

    floatx4 acc[2];
    const floatx4 zf = {0.f, 0.f, 0.f, 0.f};
    acc[0] = zf; acc[1] = zf;
    const float invN = 1.0f / NN;
    const int nt = K >> 6;   // 4

    floatx4 xa, xb2; ushort8v rv;
    xa  = *(const floatx4*)(xg);
    xb2 = *(const floatx4*)(xg + 4);
    rv  = *(const ushort8v*)(rg);
    gl2lds16(bgp0, &Bs[0][w * 1024]);
    gl2lds16(bgp1, &Bs[0][w * 1024 + 512]);
    {
        const int c = schunk * 8;
        short8 av;
        #pragma unroll
        for (int q = 0; q < 8; q++) {
            float m  = stats[c + q] * invN;
            float sq = stats[256 + c + q] * invN;
            float rs = rsqrtf(sq - m * m + 1e-5f) * g[c + q];
            float sh = be[c + q] - m * rs;
            float v = (q < 4 ? xa[q & 3] : xb2[q & 3]) * rs + sh;
            v = (v > 0.f) ? v : (expf(v) - 1.f);
            v += bf2f(rv[q]);
            av[q] = f2bf(v);
        }
        *(short8*)&As[0][w * 512 + L * 8] = av;
    }
    __syncthreads();
    int cur = 0;
    for (int t = 0; t < nt; t++) {
        floatx4 nxa, nxb2; ushort8v nrv;
        if (t + 1 < nt) {                    // issue next-tile loads before MFMA
            const int k0 = (t + 1) << 6;
            nxa  = *(const floatx4*)(xg + k0);
            nxb2 = *(const floatx4*)(xg + k0 + 4);
            nrv  = *(const ushort8v*)(rg + k0);
            gl2lds16(bgp0 + k0, &Bs[cur ^ 1][w * 1024]);
            gl2lds16(bgp1 + k0, &Bs[cur ^ 1][w * 1024 + 512]);
        }
        #pragma unroll
        for (int ks = 0; ks < 2; ks++) {
            const int sl = ((ks * 4 + quad) ^ (lr & 7)) * 8;
            short8 bfr = *(const short8*)&Bs[cur][(w * 16 + lr) * 64 + sl];
            #pragma unroll
            for (int i = 0; i < 2; i++) {
                short8 afr = *(const short8*)&As[cur][(i * 16 + lr) * 64 + sl];
                acc[i] = __builtin_amdgcn_mfma_f32_16x16x32_bf16(afr, bfr, acc[i], 0, 0, 0);
            }
        }
        if (t + 1 < nt) {                    // process next A-tile after MFMA
            const int c = schunk * 8 + ((t + 1) << 6);
            short8 av;
            #pragma unroll
            for (int q = 0; q < 8; q++) {
                float m  = stats[c + q] * invN;
                float sq = stats[256 + c + q] * invN;
                float rs = rsqrtf(sq - m * m + 1e-5f) * g[c + q];
                float sh = be[c + q] - m * rs;
                float v = (q < 4 ? nxa[q & 3] : nxb2[q & 3]) * rs + sh;
                v = (v > 0.f) ? v : (expf(v) - 1.f);
                v += bf2f(nrv[q]);
                av[q] = f2bf(v);
            }
            *(short8*)&As[cur ^ 1][w * 512 + L * 8] = av;
        }
        __syncthreads();
        cur ^= 1;
    }
    const int ccol = w * 16 + lr;
    if (ccol < Nn) {
        float bv = bias ? bias[ccol] : 0.f;
        #pragma unroll
        for (int i = 0; i < 2; i++) {
            #pragma unroll
            for (int r = 0; r < 4; r++) {
                int crow = row0 + i * 16 + quad * 4 + r;
                if (crow < M) C[(size_t)crow * Nn + ccol] = acc[i][r] + bv;
            }
        }
    }
}

// ---------------- prep: W0T/WcT transposes + edge counting ----------------
__global__ __launch_bounds__(256) void prep_a(
    const float* __restrict__ W0, const float* __restrict__ Wc,
    const int* __restrict__ edst, int E,
    short* __restrict__ W0T, short* __restrict__ WcT,
    int* __restrict__ counts)
{
    const int b = blockIdx.x, t = threadIdx.x;
    if (b < 256) {                  // W0T [256][256]
        W0T[b * 256 + t] = f2bf(W0[t * 256 + b]);
    } else if (b < 296) {           // WcT bf16 [40][256]
        int o = b - 256;
        WcT[o * 256 + t] = f2bf(Wc[t * 40 + o]);
    } else {                        // count edges
        int e = (b - 296) * 256 + t;
        if (e < E) atomicAdd(&counts[edst[e]], 1);
    }
}

// ---------------- CSR scan: 1024 thr, compile-time P=10, register-cached degs ----------
__global__ __launch_bounds__(1024) void scan_kernel(
    int* __restrict__ counts, int* __restrict__ offsets,
    int* __restrict__ cursor, int* __restrict__ elist)
{
    __shared__ int wsum[16];
    const int t = threadIdx.x, lane = t & 63, wid = t >> 6;
    constexpr int P = 10;            // NN/1024 rounded up; NN = 10000
    const int base = t * P;
    int deg[P], loc[P];
    int s = 0;
    #pragma unroll
    for (int j = 0; j < P; j++) {    // independent loads, all in flight
        int i = base + j;
        loc[j] = s;
        deg[j] = (i < NN) ? counts[i] + 1 : 0;   // +1 self-loop
        s += deg[j];
    }
    int inc = s;
    #pragma unroll
    for (int off = 1; off < 64; off <<= 1) {
        int tv = __shfl_up(inc, off, 64);
        if (lane >= off) inc += tv;
    }
    if (lane == 63) wsum[wid] = inc;
    __syncthreads();
    if (t < 16) {
        int v = wsum[t];
        int winc = v;
        #pragma unroll
        for (int off = 1; off < 16; off <<= 1) {
            int tv = __shfl_up(winc, off, 16);
            if (t >= off) winc += tv;
        }
        wsum[t] = winc - v;          // exclusive wave offset
    }
    __syncthreads();
    int excl = inc - s + wsum[wid];
    #pragma unroll
    for (int j = 0; j < P; j++) {
        int i = base + j;
        if (i < NN) {
            int o = excl + loc[j];
            counts[i] = deg[j];
            offsets[i] = o;
            elist[o] = i;            // self-loop in slot 0
            cursor[i] = o + 1;
        }
    }
}

// ---------------- fused softmax(no-max)+aggregate, layer 0 (barrier-free) ----------------
__global__ __launch_bounds__(256) void agg0_fused(
    const unsigned short* __restrict__ h0b, const float* __restrict__ s0,
    const int* __restrict__ offsets, const int* __restrict__ counts,
    const int* __restrict__ elist, float* __restrict__ out)
{
    __shared__ float pw_s[4][CHK * 8];
    __shared__ int   sn_s[4][CHK];
    const int wid = threadIdx.x >> 6, L = threadIdx.x & 63;
    const int n = blockIdx.x * 4 + wid;   // NN % 4 == 0
    float* pw = pw_s[wid];
    int*   sw = sn_s[wid];
    const int deg = counts[n], start = offsets[n];
    const int hL = L >> 3;

    floatx4 sda = *(const floatx4*)(s0 + n * 16 + 8);
    floatx4 sdb = *(const floatx4*)(s0 + n * 16 + 12);
    float sd[8] = {sda[0], sda[1], sda[2], sda[3], sdb[0], sdb[1], sdb[2], sdb[3]};
    float lp[8] = {0.f, 0.f, 0.f, 0.f, 0.f, 0.f, 0.f, 0.f};
    float a0 = 0.f, a1 = 0.f, a2 = 0.f, a3 = 0.f;

    for (int e0 = 0; e0 < deg; e0 += CHK) {
        int ch = deg - e0; if (ch > CHK) ch = CHK;
        if (L < ch) {
            int sn = elist[start + e0 + L];
            sw[L] = sn;
            floatx4 ssa = *(const floatx4*)(s0 + sn * 16);
            floatx4 ssb = *(const floatx4*)(s0 + sn * 16 + 4);
            float ss[8] = {ssa[0], ssa[1], ssa[2], ssa[3], ssb[0], ssb[1], ssb[2], ssb[3]};
            float p[8];
            #pragma unroll
            for (int h = 0; h < 8; h++) {
                float v = ss[h] + sd[h];
                v = (v > 0.f) ? v : 0.2f * v;
                p[h] = exp2f(v * LOG2E);
                lp[h] += p[h];
            }
            floatx4 p0 = {p[0], p[1], p[2], p[3]};
            floatx4 p1 = {p[4], p[5], p[6], p[7]};
            *(floatx4*)&pw[L * 8] = p0;
            *(floatx4*)&pw[L * 8 + 4] = p1;
        }
        int e = 0;
        for (; e + 2 <= ch; e += 2) {          // 2-edge unroll: two loads in flight
            float wA = pw[e * 8 + hL];
            float wB = pw[e * 8 + 8 + hL];
            ushort4 vA = *(const ushort4*)(h0b + (size_t)sw[e] * 256 + 4 * L);
            ushort4 vB = *(const ushort4*)(h0b + (size_t)sw[e + 1] * 256 + 4 * L);
            a0 += wA * bf2f(vA.x); a1 += wA * bf2f(vA.y);
            a2 += wA * bf2f(vA.z); a3 += wA * bf2f(vA.w);
            a0 += wB * bf2f(vB.x); a1 += wB * bf2f(vB.y);
            a2 += wB * bf2f(vB.z); a3 += wB * bf2f(vB.w);
        }
        if (e < ch) {
            float wA = pw[e * 8 + hL];
            ushort4 vA = *(const ushort4*)(h0b + (size_t)sw[e] * 256 + 4 * L);
            a0 += wA * bf2f(vA.x); a1 += wA * bf2f(vA.y);
            a2 += wA * bf2f(vA.z); a3 += wA * bf2f(vA.w);
        }
    }
    #pragma unroll
    for (int off = 1; off < 64; off <<= 1)
        #pragma unroll
        for (int h = 0; h < 8; h++)
            lp[h] += __shfl_xor(lp[h], off, 64);
    float inv = 1.f / lp[hL];
    floatx4 o = {a0 * inv, a1 * inv, a2 * inv, a3 * inv};
    *(floatx4*)(out + (size_t)n * 256 + 4 * L) = o;
}

// ---------------- layer-1 aggregate: ONE wave per node (all 8 heads) -----------------
__global__ __launch_bounds__(256) void agg1_full(
    const unsigned short* __restrict__ hb, const float* __restrict__ s1,
    const int* __restrict__ offsets, const int* __restrict__ counts,
    const int* __restrict__ elist, short* __restrict__ aggout)
{
    __shared__ float pw_s[4][CHK * 8];
    __shared__ int   sn_s[4][CHK];
    const int wid = threadIdx.x >> 6, L = threadIdx.x & 63;
    const int n = blockIdx.x * 4 + wid;   // NN % 4 == 0
    float* pw = pw_s[wid];
    int*   sw = sn_s[wid];
    const int deg = counts[n], start = offsets[n];

    floatx4 sda = *(const floatx4*)(s1 + n * 16 + 8);
    floatx4 sdb = *(const floatx4*)(s1 + n * 16 + 12);
    float sd[8] = {sda[0], sda[1], sda[2], sda[3], sdb[0], sdb[1], sdb[2], sdb[3]};
    float lp[8] = {0.f, 0.f, 0.f, 0.f, 0.f, 0.f, 0.f, 0.f};
    float acc[8][4];
    #pragma unroll
    for (int h = 0; h < 8; h++)
        #pragma unroll
        for (int f = 0; f < 4; f++) acc[h][f] = 0.f;

    for (int e0 = 0; e0 < deg; e0 += CHK) {
        int ch = deg - e0; if (ch > CHK) ch = CHK;
        if (L < ch) {
            int sn = elist[start + e0 + L];
            sw[L] = sn;
            floatx4 ssa = *(const floatx4*)(s1 + sn * 16);
            floatx4 ssb = *(const floatx4*)(s1 + sn * 16 + 4);
            float ss[8] = {ssa[0], ssa[1], ssa[2], ssa[3], ssb[0], ssb[1], ssb[2], ssb[3]};
            float p[8];
            #pragma unroll
            for (int h = 0; h < 8; h++) {
                float v = ss[h] + sd[h];
                v = (v > 0.f) ? v : 0.2f * v;
                p[h] = exp2f(v * LOG2E);
                lp[h] += p[h];
            }
            floatx4 p0 = {p[0], p[1], p[2], p[3]};
            floatx4 p1 = {p[4], p[5], p[6], p[7]};
            *(floatx4*)&pw[L * 8] = p0;
            *(floatx4*)&pw[L * 8 + 4] = p1;
        }
        int e = 0;
        for (; e + 2 <= ch; e += 2) {          // 2-edge unroll
            floatx4 p0A = *(const floatx4*)&pw[e * 8];
            floatx4 p1A = *(const floatx4*)&pw[e * 8 + 4];
            floatx4 p0B = *(const floatx4*)&pw[e * 8 + 8];
            floatx4 p1B = *(const floatx4*)&pw[e * 8 + 12];
            ushort4 vA = *(const ushort4*)(hb + (size_t)sw[e] * 256 + 4 * L);
            ushort4 vB = *(const ushort4*)(hb + (size_t)sw[e + 1] * 256 + 4 * L);
            float a0 = bf2f(vA.x), a1 = bf2f(vA.y), a2 = bf2f(vA.z), a3 = bf2f(vA.w);
            float b0 = bf2f(vB.x), b1 = bf2f(vB.y), b2 = bf2f(vB.z), b3 = bf2f(vB.w);
            #pragma unroll
            for (int h = 0; h < 4; h++) {
                acc[h][0] += p0A[h] * a0;     acc[h][1] += p0A[h] * a1;
                acc[h][2] += p0A[h] * a2;     acc[h][3] += p0A[h] * a3;
                acc[h + 4][0] += p1A[h] * a0; acc[h + 4][1] += p1A[h] * a1;
                acc[h + 4][2] += p1A[h] * a2; acc[h + 4][3] += p1A[h] * a3;
            }
            #pragma unroll
            for (int h = 0; h < 4; h++) {
                acc[h][0] += p0B[h] * b0;     acc[h][1] += p0B[h] * b1;
                acc[h][2] += p0B[h] * b2;     acc[h][3] += p0B[h] * b3;
                acc[h + 4][0] += p1B[h] * b0; acc[h + 4][1] += p1B[h] * b1;
                acc[h + 4][2] += p1B[h] * b2; acc[h + 4][3] += p1B[h] * b3;
            }
        }
        if (e < ch) {
            floatx4 p0A = *(const floatx4*)&pw[e * 8];
            floatx4 p1A = *(const floatx4*)&pw[e * 8 + 4];
            ushort4 vA = *(const ushort4*)(hb + (size_t)sw[e] * 256 + 4 * L);
            float a0 = bf2f(vA.x), a1 = bf2f(vA.y), a2 = bf2f(vA.z), a3 = bf2f(vA.w);
            #pragma unroll
            for (int h = 0; h < 4; h++) {
                acc[h][0] += p0A[h] * a0;     acc[h][1] += p0A[h] * a1;
                acc[h][2] += p0A[h] * a2;     acc[h][3] += p0A[h] * a3;
                acc[h + 4][0] += p1A[h] * a0; acc[h + 4][1] += p1A[h] * a1;
                acc[h + 4][2] += p1A[h] * a2; acc[h + 4][3] += p1A[h] * a3;
            }
        }
    }
    #pragma unroll
    for (int off = 1; off < 64; off <<= 1)
        #pragma unroll
        for (int h = 0; h < 8; h++)
            lp[h] += __shfl_xor(lp[h], off, 64);
    #pragma unroll
    for (int h = 0; h < 8; h++) {
        float inv = 1.f / lp[h];
        short4 o = {f2bf(acc[h][0] * inv), f2bf(acc[h][1] * inv),
                    f2bf(acc[h][2] * inv), f2bf(acc[h][3] * inv)};
        *(short4*)(aggout + (size_t)n * 2048 + h * 256 + 4 * L) = o;
    }
}

// ---------------- batchnorm stats: 64 blocks x 1024 threads, LDS-reduced ----------------
__global__ __launch_bounds__(1024) void bn_stats_kernel(
    const float* __restrict__ x, float* __restrict__ stats, int n)
{
    __shared__ float red[16][512];   // 32 KB
    const int t = threadIdx.x;
    const int sub = t >> 6, c4 = (t & 63) * 4;
    floatx4 s = {0.f, 0.f, 0.f, 0.f}, s2 = {0.f, 0.f, 0.f, 0.f};
    for (int r = blockIdx.x * 16 + sub; r < n; r += gridDim.x * 16) {
        floatx4 v = *(const floatx4*)(x + (size_t)r * 256 + c4);
        s += v; s2 += v * v;
    }
    #pragma unroll
    for (int k = 0; k < 4; k++) {
        red[sub][c4 + k] = s[k];
        red[sub][256 + c4 + k] = s2[k];
    }
    __syncthreads();
    if (t < 512) {
        float acc = 0.f;
        #pragma unroll
        for (int i = 0; i < 16; i++) acc += red[i][t];
        atomicAdd(&stats[t], acc);
    }
}

// ---------------- BN + ELU + bf16 write + layer-1 score, one block per node ----------------
__global__ __launch_bounds__(256) void bnapply_score1(
    const float* __restrict__ xg, const float* __restrict__ stats,
    const float* __restrict__ g, const float* __restrict__ be,
    const float* __restrict__ v1, short* __restrict__ hactb, float* __restrict__ s1)
{
    __shared__ float row[256];
    __shared__ float part[16][17];
    const int n = blockIdx.x, t = threadIdx.x;
    const float invN = 1.0f / NN;
    float mu = stats[t] * invN;
    float var = stats[256 + t] * invN - mu * mu;
    float v = g[t] * (xg[(size_t)n * 256 + t] - mu) * rsqrtf(var + 1e-5f) + be[t];
    v = (v > 0.f) ? v : (expf(v) - 1.f);   // ELU
    hactb[(size_t)n * 256 + t] = f2bf(v);
    row[t] = v;
    __syncthreads();
    int j = t & 15, f0 = t >> 4;
    float p = 0.f;
    #pragma unroll
    for (int k = 0; k < 16; k++)
        p += row[f0 * 16 + k] * v1[(f0 * 16 + k) * 16 + j];
    part[f0][j] = p;
    __syncthreads();
    if (t < 16) {
        float s = 0.f;
        #pragma unroll
        for (int k = 0; k < 16; k++) s += part[k][t];
        s1[n * 16 + t] = s;
    }
}

// ---------------- launch ----------------
extern "C" void kernel_launch(void* const* d_in, const int* in_sizes, int n_in,
                              void* d_out, int out_size, void* d_ws, size_t ws_size,
                              hipStream_t stream) {
    const float* x      = (const float*)d_in[0];
    const int*   eidx   = (const int*)d_in[1];
    const float* W0     = (const float*)d_in[2];
    const float* a_src0 = (const float*)d_in[3];
    const float* a_dst0 = (const float*)d_in[4];
    const float* g0     = (const float*)d_in[6];
    const float* be0    = (const float*)d_in[7];
    const float* W1     = (const float*)d_in[8];
    const float* a_src1 = (const float*)d_in[9];
    const float* a_dst1 = (const float*)d_in[10];
    const float* g1     = (const float*)d_in[12];
    const float* be1    = (const float*)d_in[13];
    const float* Wc     = (const float*)d_in[14];
    const float* bc     = (const float*)d_in[15];
    float* out = (float*)d_out;

    const int E = in_sizes[1] / 2;
    const int* esrc = eidx;
    const int* edst = eidx + E;

    char* ws = (char*)d_ws;
    size_t off = 0;
    auto alloc = [&](size_t bytes) {
        void* p = ws + off;
        off += (bytes + 255) & ~(size_t)255;
        return p;
    };
    // stats + counts contiguous -> single memset
    float* stats   = (float*)alloc(1024 * 4);
    int*   counts  = (int*)alloc(NN * 4);
    float* out1    = (float*)alloc((size_t)NN * 256 * 4);
    short* h0b     = (short*)alloc((size_t)NN * 256 * 2);
    float* s0      = (float*)alloc((size_t)NN * 16 * 4);
    float* s1      = (float*)alloc((size_t)NN * 16 * 4);
    float* v1      = (float*)alloc(4096 * 4);
    float* h_gat0  = (float*)alloc((size_t)NN * 256 * 4);
    short* hactb   = (short*)alloc((size_t)NN * 256 * 2);
    short* agg1bf  = (short*)alloc((size_t)NN * 2048 * 2);
    short* W0T     = (short*)alloc((size_t)256 * 256 * 2);
    short* W1pT    = (short*)alloc((size_t)256 * 2048 * 2);
    short* WcT     = (short*)alloc((size_t)64 * 256 * 2);
    int* offsets   = (int*)alloc((NN + 16) * 4);
    int* cursor    = (int*)alloc(NN * 4);
    int* elist     = (int*)alloc((size_t)(E + NN) * 4);

    float* stats0 = stats;
    float* stats1 = stats + 512;

    hipMemsetAsync(stats, 0, 1024 * 4 + NN * 4, stream);   // stats0+stats1+counts

    const int cntBlocks = (E + 255) / 256;

    // prep: W0T/WcT + edge counting (x cast is fused into gemm0's A-staging)
    prep_a<<<296 + cntBlocks, 256, 0, stream>>>(W0, Wc, edst, E, W0T, WcT, counts);

    // CSR scan (1024 threads, register-cached, ~4us)
    scan_kernel<<<1, 1024, 0, stream>>>(counts, offsets, cursor, elist);

    const int gy = (NN + 63) / 64;           // 157
    const int gB = 16 * ((gy + 7) / 8);      // 320 (XCD-paired swizzle groups)

    // layer-0 GEMM (f32 A + fused cast + fused scores) + scatter/v1/W1pT tails
    gemm_bf16_w128<<<gB + cntBlocks + 528, 256, 0, stream>>>(
        x, W0T, h0b,
        a_src0, a_dst0, s0,
        esrc, edst, cursor, elist, E, cntBlocks,
        W1, a_src1, a_dst1, v1, W1pT,
        gB, gy, NN, 256, 256, 1.0f);

    agg0_fused<<<NN / 4, 256, 0, stream>>>(
        (const unsigned short*)h0b, s0, offsets, counts, elist, h_gat0);
    bn_stats_kernel<<<64, 1024, 0, stream>>>(h_gat0, stats0, NN);
    bnapply_score1<<<NN, 256, 0, stream>>>(h_gat0, stats0, g0, be0, v1, hactb, s1);

    // layer 1 (BM=32 double-buffered GEMM: 626 live blocks -> 2.45/CU co-resident)
    agg1_full<<<NN / 4, 256, 0, stream>>>(
        (const unsigned short*)hactb, s1, offsets, counts, elist, agg1bf);
    const int gy1 = (NN + 31) / 32;          // 313
    const int gB1 = 16 * ((gy1 + 7) / 8);    // 640
    gemm1_db<<<gB1, 256, 0, stream>>>(
        agg1bf, W1pT, out1, stats1, gy1, NN, 256, 2048, 0.125f);

    // classifier with fused BN+ELU+residual A-staging (BM=32 -> 313 blocks, 2-phase)
    classifier_fused<<<(NN + 31) / 32, 256, 0, stream>>>(
        out1, stats1, g1, be1, (const unsigned short*)hactb,
        WcT, out, bc, NN, NCLS, 256);
}